// Round 7
// baseline (120.473 us; speedup 1.0000x reference)
//
#include <hip/hip_runtime.h>
#include <math.h>

namespace {
constexpr int kB = 65536;      // rows
constexpr int kC = 300;        // cards/options dim
constexpr int kA = 32;         // archetype dim
constexpr int kCpad = 304;     // padded W rows (300..303 zeroed)
constexpr int kWS = 36;        // W LDS row stride (floats): 16B-aligned b128, 2-way banks = free
constexpr int kBlock = 256;
constexpr int kGroups = kBlock / 16;          // 16 groups per block
constexpr int kRowsPerBlock = kGroups * 2;    // 32 rows per block (2 rows/group)
constexpr int kNI = 19;        // ceil(300/16) columns owned per lane
}

// DPP row_ror reductions within each 16-lane DPP row (thread group == DPP row).
template <int kCtrl>
__device__ __forceinline__ float dpp_rot(float x) {
    int yi = __builtin_amdgcn_update_dpp(0, __builtin_bit_cast(int, x), kCtrl, 0xf, 0xf, false);
    return __builtin_bit_cast(float, yi);
}
__device__ __forceinline__ float rsum16(float x) {
    x += dpp_rot<0x128>(x);   // row_ror:8
    x += dpp_rot<0x124>(x);   // row_ror:4
    x += dpp_rot<0x122>(x);   // row_ror:2
    x += dpp_rot<0x121>(x);   // row_ror:1
    return x;
}
__device__ __forceinline__ float rmax16(float x) {
    x = fmaxf(x, dpp_rot<0x128>(x));
    x = fmaxf(x, dpp_rot<0x124>(x));
    x = fmaxf(x, dpp_rot<0x122>(x));
    x = fmaxf(x, dpp_rot<0x121>(x));
    return x;
}

__global__ __launch_bounds__(kBlock) void draftbot_kernel(
    const float* __restrict__ X,
    const float* __restrict__ W,
    float* __restrict__ out)
{
    __shared__ float w_lds[kCpad * kWS];   // 43,776 B

    const int tid = threadIdx.x;
    const int t = tid & 15;                 // lane within 16-thread row group
    const int grp = tid >> 4;               // row group within block
    const size_t row0 = (size_t)blockIdx.x * kRowsPerBlock + grp * 2;
    const float* __restrict__ xrow0 = X + row0 * (2 * kC);
    const float* __restrict__ xrow1 = xrow0 + 2 * kC;

    // ---- phase A: issue all per-row global loads FIRST (latency hides
    //      under W staging + barrier). opts die right after omask.
    float o0[kNI], o1[kNI], cd0[kNI], cd1[kNI];
    #pragma unroll
    for (int i = 0; i < kNI; ++i) {
        const int c = t + 16 * i;
        const bool v = (c < kC);
        o0[i]  = v ? xrow0[c] : 0.0f;
        cd0[i] = v ? xrow0[kC + c] : 0.0f;
        o1[i]  = v ? xrow1[c] : 0.0f;
        cd1[i] = v ? xrow1[kC + c] : 0.0f;
    }

    // ---- stage W into LDS, vectorized (float4), zero the 4 pad rows ----
    {
        const float4* __restrict__ W4 = reinterpret_cast<const float4*>(W);
        #pragma unroll
        for (int f = tid; f < (kCpad * kA) / 4; f += kBlock) {   // 2432 float4s
            float4 v;
            if (f < (kC * kA) / 4) v = W4[f];
            else { v.x = v.y = v.z = v.w = 0.0f; }
            const int c = f >> 3;            // 8 float4 per W row
            const int a4 = (f & 7) * 4;      // float offset within row
            *reinterpret_cast<float4*>(&w_lds[c * kWS + a4]) = v;
        }
    }
    __syncthreads();

    unsigned int om0 = 0u, om1 = 0u;
    #pragma unroll
    for (int i = 0; i < kNI; ++i) {
        if (o0[i] != 0.0f) om0 |= (1u << i);
        if (o1[i] != 0.0f) om1 |= (1u << i);
    }

    const float* __restrict__ wl = w_lds + t * kWS;  // lane base (16B-aligned)

    // ---- phase B: ap partials for BOTH rows; each w4 read feeds 8 FMAs.
    //      q outer / i inner, sub-split so <=10 b128 in flight per region
    //      (bounds live set; sched_barrier pins it).
    float ap0[kA], ap1[kA];
    #pragma unroll
    for (int a = 0; a < kA; ++a) { ap0[a] = 0.0f; ap1[a] = 0.0f; }
    #pragma unroll
    for (int q = 0; q < 8; ++q) {
        #pragma unroll
        for (int i = 0; i < 10; ++i) {
            const float4 w4 = *reinterpret_cast<const float4*>(wl + i * 16 * kWS + 4 * q);
            ap0[4 * q + 0] = fmaf(cd0[i], w4.x, ap0[4 * q + 0]);
            ap0[4 * q + 1] = fmaf(cd0[i], w4.y, ap0[4 * q + 1]);
            ap0[4 * q + 2] = fmaf(cd0[i], w4.z, ap0[4 * q + 2]);
            ap0[4 * q + 3] = fmaf(cd0[i], w4.w, ap0[4 * q + 3]);
            ap1[4 * q + 0] = fmaf(cd1[i], w4.x, ap1[4 * q + 0]);
            ap1[4 * q + 1] = fmaf(cd1[i], w4.y, ap1[4 * q + 1]);
            ap1[4 * q + 2] = fmaf(cd1[i], w4.z, ap1[4 * q + 2]);
            ap1[4 * q + 3] = fmaf(cd1[i], w4.w, ap1[4 * q + 3]);
        }
        __builtin_amdgcn_sched_barrier(0);
        #pragma unroll
        for (int i = 10; i < kNI; ++i) {
            const float4 w4 = *reinterpret_cast<const float4*>(wl + i * 16 * kWS + 4 * q);
            ap0[4 * q + 0] = fmaf(cd0[i], w4.x, ap0[4 * q + 0]);
            ap0[4 * q + 1] = fmaf(cd0[i], w4.y, ap0[4 * q + 1]);
            ap0[4 * q + 2] = fmaf(cd0[i], w4.z, ap0[4 * q + 2]);
            ap0[4 * q + 3] = fmaf(cd0[i], w4.w, ap0[4 * q + 3]);
            ap1[4 * q + 0] = fmaf(cd1[i], w4.x, ap1[4 * q + 0]);
            ap1[4 * q + 1] = fmaf(cd1[i], w4.y, ap1[4 * q + 1]);
            ap1[4 * q + 2] = fmaf(cd1[i], w4.z, ap1[4 * q + 2]);
            ap1[4 * q + 3] = fmaf(cd1[i], w4.w, ap1[4 * q + 3]);
        }
        __builtin_amdgcn_sched_barrier(0);
    }

    // ---- 16-lane DPP reduce -> every lane holds full ap[], + bias ----
    #pragma unroll
    for (int a = 0; a < kA; ++a) {
        ap0[a] = rsum16(ap0[a]) + 1.0f;
        ap1[a] = rsum16(ap1[a]) + 1.0f;
    }

    // ---- phase D: scores for both rows; each w4 read feeds 8 FMAs ----
    float sc0[kNI], sc1[kNI];
    #pragma unroll
    for (int i = 0; i < kNI; ++i) { sc0[i] = 0.0f; sc1[i] = 0.0f; }
    #pragma unroll
    for (int q = 0; q < 8; ++q) {
        #pragma unroll
        for (int i = 0; i < 10; ++i) {
            const float4 w4 = *reinterpret_cast<const float4*>(wl + i * 16 * kWS + 4 * q);
            sc0[i] = fmaf(ap0[4 * q + 0], w4.x, sc0[i]);
            sc0[i] = fmaf(ap0[4 * q + 1], w4.y, sc0[i]);
            sc0[i] = fmaf(ap0[4 * q + 2], w4.z, sc0[i]);
            sc0[i] = fmaf(ap0[4 * q + 3], w4.w, sc0[i]);
            sc1[i] = fmaf(ap1[4 * q + 0], w4.x, sc1[i]);
            sc1[i] = fmaf(ap1[4 * q + 1], w4.y, sc1[i]);
            sc1[i] = fmaf(ap1[4 * q + 2], w4.z, sc1[i]);
            sc1[i] = fmaf(ap1[4 * q + 3], w4.w, sc1[i]);
        }
        __builtin_amdgcn_sched_barrier(0);
        #pragma unroll
        for (int i = 10; i < kNI; ++i) {
            const float4 w4 = *reinterpret_cast<const float4*>(wl + i * 16 * kWS + 4 * q);
            sc0[i] = fmaf(ap0[4 * q + 0], w4.x, sc0[i]);
            sc0[i] = fmaf(ap0[4 * q + 1], w4.y, sc0[i]);
            sc0[i] = fmaf(ap0[4 * q + 2], w4.z, sc0[i]);
            sc0[i] = fmaf(ap0[4 * q + 3], w4.w, sc0[i]);
            sc1[i] = fmaf(ap1[4 * q + 0], w4.x, sc1[i]);
            sc1[i] = fmaf(ap1[4 * q + 1], w4.y, sc1[i]);
            sc1[i] = fmaf(ap1[4 * q + 2], w4.z, sc1[i]);
            sc1[i] = fmaf(ap1[4 * q + 3], w4.w, sc1[i]);
        }
        __builtin_amdgcn_sched_barrier(0);
    }
    #pragma unroll
    for (int i = 0; i < kNI; ++i) {
        sc0[i] = ((om0 >> i) & 1u) ? sc0[i] : 0.0f;
        sc1[i] = ((om1 >> i) & 1u) ? sc1[i] : 0.0f;
    }

    // ---- row max (masked zeros participate, as in reference) ----
    float m0 = -INFINITY, m1 = -INFINITY;
    #pragma unroll
    for (int i = 0; i < kNI; ++i) {
        m0 = fmaxf(m0, sc0[i]);
        m1 = fmaxf(m1, sc1[i]);
    }
    m0 = rmax16(m0);
    m1 = rmax16(m1);

    // ---- sum of s * exp(x - M*s) ----
    float S0 = 0.f, S1 = 0.f;
    #pragma unroll
    for (int i = 0; i < kNI; ++i) {
        {
            const float x = sc0[i];
            const float sg = (x > 0.f ? 1.f : 0.f) - (x < 0.f ? 1.f : 0.f);
            S0 += sg * __expf(fmaf(-m0, sg, x));
        }
        {
            const float x = sc1[i];
            const float sg = (x > 0.f ? 1.f : 0.f) - (x < 0.f ? 1.f : 0.f);
            S1 += sg * __expf(fmaf(-m1, sg, x));
        }
    }
    S0 = rsum16(S0);
    S1 = rsum16(S1);
    const float lse0 = __logf(S0);
    const float lse1 = __logf(S1);

    // ---- output: s * (x - M*s - lse) ----
    float* __restrict__ orow0 = out + row0 * kC;
    float* __restrict__ orow1 = orow0 + kC;
    #pragma unroll
    for (int i = 0; i < kNI; ++i) {
        const int c = t + 16 * i;
        if (c < kC) {
            {
                const float x = sc0[i];
                const float sg = (x > 0.f ? 1.f : 0.f) - (x < 0.f ? 1.f : 0.f);
                orow0[c] = sg * (fmaf(-m0, sg, x) - lse0);
            }
            {
                const float x = sc1[i];
                const float sg = (x > 0.f ? 1.f : 0.f) - (x < 0.f ? 1.f : 0.f);
                orow1[c] = sg * (fmaf(-m1, sg, x) - lse1);
            }
        }
    }
}

extern "C" void kernel_launch(void* const* d_in, const int* in_sizes, int n_in,
                              void* d_out, int out_size, void* d_ws, size_t ws_size,
                              hipStream_t stream) {
    const float* X = (const float*)d_in[0];
    const float* W = (const float*)d_in[1];
    float* out = (float*)d_out;
    dim3 grid(kB / kRowsPerBlock);   // 2048 blocks
    dim3 block(kBlock);              // 256 threads
    hipLaunchKernelGGL(draftbot_kernel, grid, block, 0, stream, X, W, out);
}

// Round 8
// 95.572 us; speedup vs baseline: 1.2605x; 1.2605x over previous
//
#include <hip/hip_runtime.h>
#include <hip/hip_fp16.h>
#include <math.h>

namespace {
constexpr int kB = 65536;      // rows
constexpr int kC = 300;        // cards/options dim
constexpr int kA = 32;         // archetype dim
constexpr int kCpad = 304;     // padded W rows (300..303 zeroed)
constexpr int kWSh = 36;       // W LDS row stride in HALVES: 72B rows, 8B-aligned b64,
                               // lane-t bank = (t*18)%32 -> 16 distinct banks, conflict-free
constexpr int kBlock = 512;
constexpr int kRowsPerBlock = kBlock / 16;  // 32 rows per block (1 row per 16-lane group)
constexpr int kNI = 19;        // ceil(300/16) columns owned per lane
}

// DPP row_ror reductions within each 16-lane DPP row (thread group == DPP row).
template <int kCtrl>
__device__ __forceinline__ float dpp_rot(float x) {
    int yi = __builtin_amdgcn_update_dpp(0, __builtin_bit_cast(int, x), kCtrl, 0xf, 0xf, false);
    return __builtin_bit_cast(float, yi);
}
__device__ __forceinline__ float rsum16(float x) {
    x += dpp_rot<0x128>(x);   // row_ror:8
    x += dpp_rot<0x124>(x);   // row_ror:4
    x += dpp_rot<0x122>(x);   // row_ror:2
    x += dpp_rot<0x121>(x);   // row_ror:1
    return x;
}
__device__ __forceinline__ float rmax16(float x) {
    x = fmaxf(x, dpp_rot<0x128>(x));
    x = fmaxf(x, dpp_rot<0x124>(x));
    x = fmaxf(x, dpp_rot<0x122>(x));
    x = fmaxf(x, dpp_rot<0x121>(x));
    return x;
}

__global__ __launch_bounds__(kBlock) void draftbot_kernel(
    const float* __restrict__ X,
    const float* __restrict__ W,
    float* __restrict__ out)
{
    __shared__ __half w_lds[kCpad * kWSh];   // 21,888 B -> LDS no longer caps occupancy

    const int tid = threadIdx.x;
    const int t = tid & 15;                 // lane within 16-thread row group
    const int grp = tid >> 4;               // row group within block
    const size_t row = (size_t)blockIdx.x * kRowsPerBlock + grp;
    const float* __restrict__ xrow = X + row * (2 * kC);

    // ---- phase A: issue all per-row global loads FIRST (latency hides
    //      under W staging + barrier). opts[] dies right after omask.
    float opts[kNI];
    float cards[kNI];
    #pragma unroll
    for (int i = 0; i < kNI; ++i) {
        const int c = t + 16 * i;
        const bool v = (c < kC);
        opts[i]  = v ? xrow[c] : 0.0f;
        cards[i] = v ? xrow[kC + c] : 0.0f;
    }

    // ---- stage W into LDS as f16, vectorized; zero the 4 pad rows ----
    {
        const float4* __restrict__ W4 = reinterpret_cast<const float4*>(W);
        #pragma unroll
        for (int f = tid; f < (kCpad * kA) / 4; f += kBlock) {   // 2432 float4s
            float4 v;
            if (f < (kC * kA) / 4) v = W4[f];
            else { v.x = v.y = v.z = v.w = 0.0f; }
            const int c = f >> 3;            // 8 quads per W row
            const int a4 = (f & 7) * 4;      // element offset within row
            const __half2 h01 = __halves2half2(__float2half_rn(v.x), __float2half_rn(v.y));
            const __half2 h23 = __halves2half2(__float2half_rn(v.z), __float2half_rn(v.w));
            int2 iv;
            iv.x = __builtin_bit_cast(int, h01);
            iv.y = __builtin_bit_cast(int, h23);
            *reinterpret_cast<int2*>(&w_lds[c * kWSh + a4]) = iv;   // 8B store, aligned
        }
    }
    __syncthreads();

    unsigned int omask = 0u;
    #pragma unroll
    for (int i = 0; i < kNI; ++i)
        if (opts[i] != 0.0f) omask |= (1u << i);

    const __half* __restrict__ wl = w_lds + t * kWSh;  // lane base (72B stride, 8B-aligned)

    // ---- phase B: ap partial accumulation, q OUTER / i inner.
    //      Per q-block: 19 independent b64 reads; f16 values feed v_fma_mix_f32.
    float ap[kA];
    #pragma unroll
    for (int a = 0; a < kA; ++a) ap[a] = 0.0f;
    #pragma unroll
    for (int q = 0; q < 8; ++q) {
        #pragma unroll
        for (int i = 0; i < kNI; ++i) {
            const int2 rv = *reinterpret_cast<const int2*>(wl + i * 16 * kWSh + 4 * q);
            const __half2 h01 = __builtin_bit_cast(__half2, rv.x);
            const __half2 h23 = __builtin_bit_cast(__half2, rv.y);
            const float cd = cards[i];
            ap[4 * q + 0] = fmaf(cd, __low2float(h01),  ap[4 * q + 0]);
            ap[4 * q + 1] = fmaf(cd, __high2float(h01), ap[4 * q + 1]);
            ap[4 * q + 2] = fmaf(cd, __low2float(h23),  ap[4 * q + 2]);
            ap[4 * q + 3] = fmaf(cd, __high2float(h23), ap[4 * q + 3]);
        }
        __builtin_amdgcn_sched_barrier(0);
    }

    // ---- 16-lane DPP reduce -> every lane holds full ap[], + bias ----
    #pragma unroll
    for (int a = 0; a < kA; ++a) ap[a] = rsum16(ap[a]) + 1.0f;

    // ---- phase D: scores, q OUTER / i inner, accumulate into sc[i] ----
    float sc[kNI];
    #pragma unroll
    for (int i = 0; i < kNI; ++i) sc[i] = 0.0f;
    #pragma unroll
    for (int q = 0; q < 8; ++q) {
        #pragma unroll
        for (int i = 0; i < kNI; ++i) {
            const int2 rv = *reinterpret_cast<const int2*>(wl + i * 16 * kWSh + 4 * q);
            const __half2 h01 = __builtin_bit_cast(__half2, rv.x);
            const __half2 h23 = __builtin_bit_cast(__half2, rv.y);
            sc[i] = fmaf(ap[4 * q + 0], __low2float(h01),  sc[i]);
            sc[i] = fmaf(ap[4 * q + 1], __high2float(h01), sc[i]);
            sc[i] = fmaf(ap[4 * q + 2], __low2float(h23),  sc[i]);
            sc[i] = fmaf(ap[4 * q + 3], __high2float(h23), sc[i]);
        }
        __builtin_amdgcn_sched_barrier(0);
    }
    #pragma unroll
    for (int i = 0; i < kNI; ++i)
        sc[i] = ((omask >> i) & 1u) ? sc[i] : 0.0f;

    // ---- row max (masked zeros participate, as in reference) ----
    float m = -INFINITY;
    #pragma unroll
    for (int i = 0; i < kNI; ++i) m = fmaxf(m, sc[i]);
    m = rmax16(m);

    // ---- sum of s * exp(x - M*s) ----
    float S = 0.f;
    #pragma unroll
    for (int i = 0; i < kNI; ++i) {
        const float x = sc[i];
        const float sg = (x > 0.f ? 1.f : 0.f) - (x < 0.f ? 1.f : 0.f);
        S += sg * __expf(fmaf(-m, sg, x));
    }
    S = rsum16(S);
    const float lse = __logf(S);

    // ---- output: s * (x - M*s - lse) ----
    float* __restrict__ orow = out + row * kC;
    #pragma unroll
    for (int i = 0; i < kNI; ++i) {
        const int c = t + 16 * i;
        if (c < kC) {
            const float x = sc[i];
            const float sg = (x > 0.f ? 1.f : 0.f) - (x < 0.f ? 1.f : 0.f);
            orow[c] = sg * (fmaf(-m, sg, x) - lse);
        }
    }
}

extern "C" void kernel_launch(void* const* d_in, const int* in_sizes, int n_in,
                              void* d_out, int out_size, void* d_ws, size_t ws_size,
                              hipStream_t stream) {
    const float* X = (const float*)d_in[0];
    const float* W = (const float*)d_in[1];
    float* out = (float*)d_out;
    dim3 grid(kB / kRowsPerBlock);   // 2048 blocks
    dim3 block(kBlock);              // 512 threads
    hipLaunchKernelGGL(draftbot_kernel, grid, block, 0, stream, X, W, out);
}